// Round 7
// baseline (172.034 us; speedup 1.0000x reference)
//
#include <hip/hip_runtime.h>
#include <hip/hip_bf16.h>
#include <stdint.h>

// Problem: N=512, R=4, B=65536, OUT=512
// out = relu(x @ W + b1) @ W2 + b2,  W = krylov_recon(G,H) (512x512)

typedef __attribute__((ext_vector_type(8))) short bf16x8;   // MFMA A/B frag (4 VGPR)
typedef __attribute__((ext_vector_type(4))) float f32x4;    // MFMA C/D frag
typedef __attribute__((ext_vector_type(4))) unsigned int u32x4;

__device__ __forceinline__ unsigned short f2bf(float f) {
  return __builtin_bit_cast(unsigned short, __float2bfloat16(f));
}

// ---------------------------------------------------------------------------
// Kernel 1: W partials.  W[a,b] = sum_i sum_j G[(a-j)&511,i]*sgn(b+j)*H[(b+j)&511,i]
// ---------------------------------------------------------------------------
__global__ void build_w_partials(const float* __restrict__ G, const float* __restrict__ H,
                                 float* __restrict__ Wp) {
  __shared__ float4 Gs[512];
  __shared__ float4 Hs[512];
  const int t = threadIdx.x;  // 256
  const float4* G4 = (const float4*)G;
  const float4* H4 = (const float4*)H;
  for (int i = t; i < 512; i += 256) { Gs[i] = G4[i]; Hs[i] = H4[i]; }
  __syncthreads();

  const int blk  = blockIdx.x;      // 0..255
  const int tile = blk >> 2;
  const int jc   = blk & 3;
  const int a0 = (tile >> 3) << 6;
  const int b0 = (tile & 7) << 6;
  const int ab = a0 + ((t >> 4) << 2);
  const int bb = b0 + ((t & 15) << 2);

  float acc[4][4] = {};
  const int j0 = jc << 7;
  for (int jj = 0; jj < 128; ++jj) {
    const int j = j0 + jj;
    float4 Ga[4], Hb[4];
#pragma unroll
    for (int r = 0; r < 4; ++r) Ga[r] = Gs[(ab + r - j) & 511];
#pragma unroll
    for (int c = 0; c < 4; ++c) {
      const int idx = bb + c + j;
      const float s = (idx >= 512) ? -1.f : 1.f;
      const float4 hv = Hs[idx & 511];
      Hb[c].x = hv.x * s; Hb[c].y = hv.y * s; Hb[c].z = hv.z * s; Hb[c].w = hv.w * s;
    }
#pragma unroll
    for (int r = 0; r < 4; ++r)
#pragma unroll
      for (int c = 0; c < 4; ++c)
        acc[r][c] += Ga[r].x * Hb[c].x + Ga[r].y * Hb[c].y +
                     Ga[r].z * Hb[c].z + Ga[r].w * Hb[c].w;
  }

  float* outp = Wp + (size_t)jc * 262144;
#pragma unroll
  for (int r = 0; r < 4; ++r)
#pragma unroll
    for (int c = 0; c < 4; ++c)
      outp[(size_t)(ab + r) * 512 + (bb + c)] = acc[r][c];
}

// ---------------------------------------------------------------------------
// Kernel 2: reduce 4 partials, store W transposed bf16: Wt[n=b][k=a]
// ---------------------------------------------------------------------------
__global__ void reduce_transpose_w(const float* __restrict__ Wp, unsigned short* __restrict__ Wt) {
  const int idx = blockIdx.x * 256 + threadIdx.x;
  const int b = idx >> 9, a = idx & 511;
  const size_t o = (size_t)a * 512 + b;
  float s = Wp[o] + Wp[o + 262144] + Wp[o + 524288] + Wp[o + 786432];
  Wt[(size_t)b * 512 + a] = f2bf(s);
}

// ---------------------------------------------------------------------------
// Kernel 3: W2 (512x512 f32 [k][n]) -> W2t bf16 [n][k]
// ---------------------------------------------------------------------------
__global__ void transpose_convert_w2(const float* __restrict__ W2, unsigned short* __restrict__ W2t) {
  const int idx = blockIdx.x * 256 + threadIdx.x;
  const int n = idx >> 9, k = idx & 511;
  W2t[(size_t)n * 512 + k] = f2bf(W2[(size_t)k * 512 + n]);
}

// ---------------------------------------------------------------------------
// Ring GEMM: C[M x 512] = epi(A[M x 512] @ Bt^T + bias)
// BM=BN=256, BK=32, NT=16. 8 waves (2M x 4N), per-wave 128x64 (acc 8x4).
// ONE barrier + ONE lgkmcnt(0) + ONE counted vmcnt per K-tile; 32 MFMA
// between barriers. Deep gll ring:
//   AF32 (GEMM1): 3-slot ring x 48KB = 144KB, distance 2, gate vmcnt(6)
//   bf16 (GEMM2): 4-slot ring x 32KB = 128KB, distance 3, gate vmcnt(8)
// Slot/tile loop fully unrolled -> compile-time slots and gate immediates.
// Swizzles identical to r6 (correctness-verified):
//   f32 rows (128B):  byte = r*128 + ((c ^ (r&7))<<4)
//   bf16 rows (64B):  byte = r*64  + ((c ^ ((r>>1)&3))<<4)
// gll = linear LDS dest + inverse-permuted global source (rule 21).
// ---------------------------------------------------------------------------
template <bool AF32>
__global__ __launch_bounds__(512, 2) void gemm_ring(
    const void* __restrict__ Ap, const unsigned short* __restrict__ Bt,
    const float* __restrict__ bias, void* __restrict__ Cp) {
  constexpr int NT    = 16;
  constexpr int RING  = AF32 ? 3 : 4;
  constexpr int ASLOT = AF32 ? 32768 : 16384;
  constexpr int BSLOT = 16384;
  constexpr int SLOT  = ASLOT + BSLOT;         // 48K / 32K
  constexpr int NAG   = AF32 ? 4 : 2;          // A glls / thread / tile
  constexpr int GPT   = NAG + 2;               // glls / thread / tile (A+B)

  __shared__ __attribute__((aligned(16))) char lds[RING * SLOT];  // 144K / 128K

  const int tid  = threadIdx.x;
  const int lane = tid & 63;
  const int w    = tid >> 6;          // 0..7
  const int wm   = w & 1;             // M half (128 rows)
  const int wn   = w >> 1;            // 0..3 (64 n-cols each)
  const int lr   = lane & 15;
  const int lq   = lane >> 4;

  const int bid = (int)blockIdx.x;                // 512 blocks
  const int wg  = (bid & 7) * 64 + (bid >> 3);    // XCD-bijective (512%8==0)
  const int m0  = (wg >> 1) << 8;
  const int n0  = (wg & 1) << 8;

  // ---- bias first; drain so the vm FIFO holds ONLY staging glls ----
  float bv[4];
#pragma unroll
  for (int ni = 0; ni < 4; ++ni) bv[ni] = bias[n0 + wn * 64 + ni * 16 + lr];
  asm volatile("s_waitcnt vmcnt(0)" ::: "memory");

  // ---- staging source byte offsets (inverse-permuted per 16B chunk) ----
  size_t aSrcOff[NAG];
  if constexpr (AF32) {
#pragma unroll
    for (int i = 0; i < 4; ++i) {
      const int cl = i * 512 + tid;              // chunk 0..2047
      const int r = cl >> 3, d = cl & 7;
      aSrcOff[i] = (size_t)r * 2048 + (size_t)((d ^ (r & 7)) << 4);
    }
  } else {
#pragma unroll
    for (int i = 0; i < 2; ++i) {
      const int cl = i * 512 + tid;              // chunk 0..1023
      const int r = cl >> 2, d = cl & 3;
      aSrcOff[i] = (size_t)r * 1024 + (size_t)((d ^ ((r >> 1) & 3)) << 4);
    }
  }
  size_t bSrcOff[2];
#pragma unroll
  for (int i = 0; i < 2; ++i) {
    const int cl = i * 512 + tid;
    const int r = cl >> 2, d = cl & 3;
    bSrcOff[i] = (size_t)r * 1024 + (size_t)((d ^ ((r >> 1) & 3)) << 4);
  }
  const char* aBase = (const char*)Ap + (size_t)m0 * (AF32 ? 2048 : 1024);
  const char* bBase = (const char*)Bt + (size_t)n0 * 1024;

  auto stage = [&](int kt) {                     // kt compile-time when unrolled
    char* sb = lds + (kt % RING) * SLOT;
#pragma unroll
    for (int i = 0; i < NAG; ++i)
      __builtin_amdgcn_global_load_lds(
        (const __attribute__((address_space(1))) void*)
          (aBase + aSrcOff[i] + (size_t)kt * (AF32 ? 128 : 64)),
        (__attribute__((address_space(3))) void*)(sb + i * 8192 + w * 1024),
        16, 0, 0);
#pragma unroll
    for (int i = 0; i < 2; ++i)
      __builtin_amdgcn_global_load_lds(
        (const __attribute__((address_space(1))) void*)
          (bBase + bSrcOff[i] + (size_t)kt * 64),
        (__attribute__((address_space(3))) void*)(sb + ASLOT + i * 8192 + w * 1024),
        16, 0, 0);
  };

  // ---- frag ds_read offsets (conflict-free per consecutive-8 lanes) ----
  int offA[8], offB[4];
#pragma unroll
  for (int mi = 0; mi < 8; ++mi) {
    const int r = wm * 128 + mi * 16 + lr;
    if constexpr (AF32)
      offA[mi] = r * 128 + (((2 * lq) ^ (r & 7)) << 4);    // hi read = ^16
    else
      offA[mi] = r * 64 + ((lq ^ ((r >> 1) & 3)) << 4);
  }
#pragma unroll
  for (int ni = 0; ni < 4; ++ni) {
    const int rb = wn * 64 + ni * 16 + lr;
    offB[ni] = ASLOT + rb * 64 + ((lq ^ ((rb >> 1) & 3)) << 4);
  }

  f32x4 acc[8][4];
  const f32x4 vz = {0.f, 0.f, 0.f, 0.f};
#pragma unroll
  for (int i = 0; i < 8; ++i)
#pragma unroll
    for (int j = 0; j < 4; ++j) acc[i][j] = vz;

  // ---- prologue: fill ring except one slot; confirm tile 0 ----
#pragma unroll
  for (int p = 0; p < RING - 1; ++p) stage(p);
  if constexpr (AF32) asm volatile("s_waitcnt vmcnt(6)" ::: "memory");
  else                asm volatile("s_waitcnt vmcnt(8)" ::: "memory");
  __builtin_amdgcn_s_barrier();
  __builtin_amdgcn_sched_barrier(0);

#pragma unroll
  for (int t = 0; t < NT; ++t) {
    // stage into slot (t-1)%RING -- consumption confirmed by barrier(t-1)
    if (t + RING - 1 < NT) stage(t + RING - 1);

    const char* sb = lds + (t % RING) * SLOT;
    bf16x8 bfr[4];
#pragma unroll
    for (int ni = 0; ni < 4; ++ni) bfr[ni] = *(const bf16x8*)(sb + offB[ni]);

    if constexpr (AF32) {
      // ---- first m-half: read+cvt mi0-3, 16 MFMA ----
      f32x4 lo[4], hi[4];
#pragma unroll
      for (int k = 0; k < 4; ++k) {
        lo[k] = *(const f32x4*)(sb + offA[k]);
        hi[k] = *(const f32x4*)(sb + (offA[k] ^ 16));
      }
      asm volatile("s_waitcnt lgkmcnt(0)" ::: "memory");
      __builtin_amdgcn_sched_barrier(0);
      bf16x8 afr[4];
#pragma unroll
      for (int k = 0; k < 4; ++k) {
        unsigned int w0, w1, w2, w3;
        asm("v_cvt_pk_bf16_f32 %0, %1, %2" : "=v"(w0) : "v"(lo[k].x), "v"(lo[k].y));
        asm("v_cvt_pk_bf16_f32 %0, %1, %2" : "=v"(w1) : "v"(lo[k].z), "v"(lo[k].w));
        asm("v_cvt_pk_bf16_f32 %0, %1, %2" : "=v"(w2) : "v"(hi[k].x), "v"(hi[k].y));
        asm("v_cvt_pk_bf16_f32 %0, %1, %2" : "=v"(w3) : "v"(hi[k].z), "v"(hi[k].w));
        u32x4 pw = {w0, w1, w2, w3};
        afr[k] = __builtin_bit_cast(bf16x8, pw);
      }
      __builtin_amdgcn_s_setprio(1);
#pragma unroll
      for (int k = 0; k < 4; ++k)
#pragma unroll
        for (int ni = 0; ni < 4; ++ni)
          acc[k][ni] = __builtin_amdgcn_mfma_f32_16x16x32_bf16(afr[k], bfr[ni], acc[k][ni], 0, 0, 0);
      __builtin_amdgcn_s_setprio(0);
      // ---- second m-half: read+cvt mi4-7, 16 MFMA ----
#pragma unroll
      for (int k = 0; k < 4; ++k) {
        lo[k] = *(const f32x4*)(sb + offA[4 + k]);
        hi[k] = *(const f32x4*)(sb + (offA[4 + k] ^ 16));
      }
      asm volatile("s_waitcnt lgkmcnt(0)" ::: "memory");
      __builtin_amdgcn_sched_barrier(0);
#pragma unroll
      for (int k = 0; k < 4; ++k) {
        unsigned int w0, w1, w2, w3;
        asm("v_cvt_pk_bf16_f32 %0, %1, %2" : "=v"(w0) : "v"(lo[k].x), "v"(lo[k].y));
        asm("v_cvt_pk_bf16_f32 %0, %1, %2" : "=v"(w1) : "v"(lo[k].z), "v"(lo[k].w));
        asm("v_cvt_pk_bf16_f32 %0, %1, %2" : "=v"(w2) : "v"(hi[k].x), "v"(hi[k].y));
        asm("v_cvt_pk_bf16_f32 %0, %1, %2" : "=v"(w3) : "v"(hi[k].z), "v"(hi[k].w));
        u32x4 pw = {w0, w1, w2, w3};
        afr[k] = __builtin_bit_cast(bf16x8, pw);
      }
      __builtin_amdgcn_s_setprio(1);
#pragma unroll
      for (int k = 0; k < 4; ++k)
#pragma unroll
        for (int ni = 0; ni < 4; ++ni)
          acc[4 + k][ni] = __builtin_amdgcn_mfma_f32_16x16x32_bf16(afr[k], bfr[ni], acc[4 + k][ni], 0, 0, 0);
      __builtin_amdgcn_s_setprio(0);
    } else {
      bf16x8 afr[8];
#pragma unroll
      for (int k = 0; k < 8; ++k) afr[k] = *(const bf16x8*)(sb + offA[k]);
      asm volatile("s_waitcnt lgkmcnt(0)" ::: "memory");
      __builtin_amdgcn_sched_barrier(0);
      __builtin_amdgcn_s_setprio(1);
#pragma unroll
      for (int k = 0; k < 8; ++k)
#pragma unroll
        for (int ni = 0; ni < 4; ++ni)
          acc[k][ni] = __builtin_amdgcn_mfma_f32_16x16x32_bf16(afr[k], bfr[ni], acc[k][ni], 0, 0, 0);
      __builtin_amdgcn_s_setprio(0);
    }

    // ---- per-tile gate: tile t+1 landed; deeper prefetches stay in flight ----
    if (t < NT - 1) {
      const int rem  = NT - 2 - t;                      // tiles staged beyond t+1
      const int keep = (rem < RING - 2 ? rem : RING - 2) * GPT;
      if (keep == 8)      asm volatile("s_waitcnt vmcnt(8)" ::: "memory");
      else if (keep == 6) asm volatile("s_waitcnt vmcnt(6)" ::: "memory");
      else if (keep == 4) asm volatile("s_waitcnt vmcnt(4)" ::: "memory");
      else                asm volatile("s_waitcnt vmcnt(0)" ::: "memory");
    }
    __builtin_amdgcn_s_barrier();
    __builtin_amdgcn_sched_barrier(0);
  }

  // ---- epilogue: C/D col=lr, row=lq*4+i ----
#pragma unroll
  for (int ni = 0; ni < 4; ++ni) {
    const int gc = n0 + wn * 64 + ni * 16 + lr;
#pragma unroll
    for (int mi = 0; mi < 8; ++mi) {
      const int gr = m0 + wm * 128 + mi * 16 + lq * 4;
      const f32x4 v = acc[mi][ni];
#pragma unroll
      for (int i = 0; i < 4; ++i) {
        const float val = v[i] + bv[ni];
        if constexpr (AF32)
          ((unsigned short*)Cp)[(size_t)(gr + i) * 512 + gc] = f2bf(val > 0.f ? val : 0.f);
        else
          ((float*)Cp)[(size_t)(gr + i) * 512 + gc] = val;
      }
    }
  }
}

// ---------------------------------------------------------------------------
extern "C" void kernel_launch(void* const* d_in, const int* in_sizes, int n_in,
                              void* d_out, int out_size, void* d_ws, size_t ws_size,
                              hipStream_t stream) {
  (void)in_sizes; (void)n_in; (void)out_size; (void)ws_size;
  const float* x  = (const float*)d_in[0];  // (65536, 512)
  const float* G  = (const float*)d_in[1];  // (512, 4)
  const float* H  = (const float*)d_in[2];  // (512, 4)
  const float* b1 = (const float*)d_in[3];  // (512,)
  const float* W2 = (const float*)d_in[4];  // (512, 512)
  const float* b2 = (const float*)d_in[5];  // (512,)
  float* out = (float*)d_out;               // (65536, 512) f32

  char* ws = (char*)d_ws;                                    // ~72.4 MB
  unsigned short* h   = (unsigned short*)ws;                 // 67,108,864 B
  unsigned short* Wt  = (unsigned short*)(ws + 67108864);    //    524,288 B
  unsigned short* W2t = (unsigned short*)(ws + 67633152);    //    524,288 B
  float*          Wp  = (float*)(ws + 68157440);             //  4,194,304 B

  build_w_partials<<<256, 256, 0, stream>>>(G, H, Wp);
  reduce_transpose_w<<<1024, 256, 0, stream>>>(Wp, Wt);
  transpose_convert_w2<<<1024, 256, 0, stream>>>(W2, W2t);
  gemm_ring<true><<<512, 512, 0, stream>>>((const void*)x, Wt, b1, (void*)h);
  gemm_ring<false><<<512, 512, 0, stream>>>((const void*)h, W2t, b2, (void*)out);
}

// Round 8
// 171.896 us; speedup vs baseline: 1.0008x; 1.0008x over previous
//
#include <hip/hip_runtime.h>
#include <hip/hip_bf16.h>
#include <stdint.h>

// Problem: N=512, R=4, B=65536, OUT=512
// out = relu(x @ W + b1) @ W2 + b2,  W = krylov_recon(G,H) (512x512)

typedef __attribute__((ext_vector_type(8))) short bf16x8;   // MFMA A/B frag (4 VGPR)
typedef __attribute__((ext_vector_type(4))) float f32x4;    // MFMA C/D frag
typedef __attribute__((ext_vector_type(4))) unsigned int u32x4;

__device__ __forceinline__ unsigned short f2bf(float f) {
  return __builtin_bit_cast(unsigned short, __float2bfloat16(f));
}

// ---------------------------------------------------------------------------
// Kernel 1: W partials.  W[a,b] = sum_i sum_j G[(a-j)&511,i]*sgn(b+j)*H[(b+j)&511,i]
// ---------------------------------------------------------------------------
__global__ void build_w_partials(const float* __restrict__ G, const float* __restrict__ H,
                                 float* __restrict__ Wp) {
  __shared__ float4 Gs[512];
  __shared__ float4 Hs[512];
  const int t = threadIdx.x;  // 256
  const float4* G4 = (const float4*)G;
  const float4* H4 = (const float4*)H;
  for (int i = t; i < 512; i += 256) { Gs[i] = G4[i]; Hs[i] = H4[i]; }
  __syncthreads();

  const int blk  = blockIdx.x;      // 0..255
  const int tile = blk >> 2;
  const int jc   = blk & 3;
  const int a0 = (tile >> 3) << 6;
  const int b0 = (tile & 7) << 6;
  const int ab = a0 + ((t >> 4) << 2);
  const int bb = b0 + ((t & 15) << 2);

  float acc[4][4] = {};
  const int j0 = jc << 7;
  for (int jj = 0; jj < 128; ++jj) {
    const int j = j0 + jj;
    float4 Ga[4], Hb[4];
#pragma unroll
    for (int r = 0; r < 4; ++r) Ga[r] = Gs[(ab + r - j) & 511];
#pragma unroll
    for (int c = 0; c < 4; ++c) {
      const int idx = bb + c + j;
      const float s = (idx >= 512) ? -1.f : 1.f;
      const float4 hv = Hs[idx & 511];
      Hb[c].x = hv.x * s; Hb[c].y = hv.y * s; Hb[c].z = hv.z * s; Hb[c].w = hv.w * s;
    }
#pragma unroll
    for (int r = 0; r < 4; ++r)
#pragma unroll
      for (int c = 0; c < 4; ++c)
        acc[r][c] += Ga[r].x * Hb[c].x + Ga[r].y * Hb[c].y +
                     Ga[r].z * Hb[c].z + Ga[r].w * Hb[c].w;
  }

  float* outp = Wp + (size_t)jc * 262144;
#pragma unroll
  for (int r = 0; r < 4; ++r)
#pragma unroll
    for (int c = 0; c < 4; ++c)
      outp[(size_t)(ab + r) * 512 + (bb + c)] = acc[r][c];
}

// ---------------------------------------------------------------------------
// Kernel 2: reduce 4 partials, store W transposed bf16: Wt[n=b][k=a]
// ---------------------------------------------------------------------------
__global__ void reduce_transpose_w(const float* __restrict__ Wp, unsigned short* __restrict__ Wt) {
  const int idx = blockIdx.x * 256 + threadIdx.x;
  const int b = idx >> 9, a = idx & 511;
  const size_t o = (size_t)a * 512 + b;
  float s = Wp[o] + Wp[o + 262144] + Wp[o + 524288] + Wp[o + 786432];
  Wt[(size_t)b * 512 + a] = f2bf(s);
}

// ---------------------------------------------------------------------------
// Kernel 3: W2 (512x512 f32 [k][n]) -> W2t bf16 [n][k]
// ---------------------------------------------------------------------------
__global__ void transpose_convert_w2(const float* __restrict__ W2, unsigned short* __restrict__ W2t) {
  const int idx = blockIdx.x * 256 + threadIdx.x;
  const int n = idx >> 9, k = idx & 511;
  W2t[(size_t)n * 512 + k] = f2bf(W2[(size_t)k * 512 + n]);
}

// ---------------------------------------------------------------------------
// Ring GEMM with in-wave pipelined tile body.
// C[M x 512] = epi(A[M x 512] @ Bt^T + bias)
// BM=BN=256, BK=32, NT=16. 8 waves (2M x 4N), per-wave 128x64 (acc 8x4).
// ONE barrier + ONE counted vmcnt per K-tile; NO lgkmcnt(0) walls inside a
// tile -- frag-group g+1's ds_reads are issued before MFMA group g and the
// compiler's fine-grained counted lgkm waits provide the read<->MFMA overlap
// (m97 regime). Cross-tile hazards guarded exactly as r7 (passed):
// memory-clobber vmcnt gate + raw s_barrier + sched_barrier(0).
//   AF32 (GEMM1): 3-slot ring x 48KB = 144KB, distance 2, gate vmcnt(6)
//   bf16 (GEMM2): 4-slot ring x 32KB = 128KB, distance 3, gate vmcnt(8)
// Swizzles identical to r6/r7 (correctness-verified):
//   f32 rows (128B):  byte = r*128 + ((c ^ (r&7))<<4)
//   bf16 rows (64B):  byte = r*64  + ((c ^ ((r>>1)&3))<<4)
// gll = linear LDS dest + inverse-permuted global source (rule 21).
// ---------------------------------------------------------------------------
template <bool AF32>
__global__ __launch_bounds__(512, 2) void gemm_ring(
    const void* __restrict__ Ap, const unsigned short* __restrict__ Bt,
    const float* __restrict__ bias, void* __restrict__ Cp) {
  constexpr int NT    = 16;
  constexpr int RING  = AF32 ? 3 : 4;
  constexpr int ASLOT = AF32 ? 32768 : 16384;
  constexpr int BSLOT = 16384;
  constexpr int SLOT  = ASLOT + BSLOT;         // 48K / 32K
  constexpr int NAG   = AF32 ? 4 : 2;          // A glls / thread / tile
  constexpr int GPT   = NAG + 2;               // glls / thread / tile (A+B)

  __shared__ __attribute__((aligned(16))) char lds[RING * SLOT];  // 144K / 128K

  const int tid  = threadIdx.x;
  const int lane = tid & 63;
  const int w    = tid >> 6;          // 0..7
  const int wm   = w & 1;             // M half (128 rows)
  const int wn   = w >> 1;            // 0..3 (64 n-cols each)
  const int lr   = lane & 15;
  const int lq   = lane >> 4;

  const int bid = (int)blockIdx.x;                // 512 blocks
  const int wg  = (bid & 7) * 64 + (bid >> 3);    // XCD-bijective (512%8==0)
  const int m0  = (wg >> 1) << 8;
  const int n0  = (wg & 1) << 8;

  // ---- bias first; drain so the vm FIFO holds ONLY staging glls ----
  float bv[4];
#pragma unroll
  for (int ni = 0; ni < 4; ++ni) bv[ni] = bias[n0 + wn * 64 + ni * 16 + lr];
  asm volatile("s_waitcnt vmcnt(0) lgkmcnt(0)" ::: "memory");

  // ---- staging source byte offsets (inverse-permuted per 16B chunk) ----
  size_t aSrcOff[NAG];
  if constexpr (AF32) {
#pragma unroll
    for (int i = 0; i < 4; ++i) {
      const int cl = i * 512 + tid;              // chunk 0..2047
      const int r = cl >> 3, d = cl & 7;
      aSrcOff[i] = (size_t)r * 2048 + (size_t)((d ^ (r & 7)) << 4);
    }
  } else {
#pragma unroll
    for (int i = 0; i < 2; ++i) {
      const int cl = i * 512 + tid;              // chunk 0..1023
      const int r = cl >> 2, d = cl & 3;
      aSrcOff[i] = (size_t)r * 1024 + (size_t)((d ^ ((r >> 1) & 3)) << 4);
    }
  }
  size_t bSrcOff[2];
#pragma unroll
  for (int i = 0; i < 2; ++i) {
    const int cl = i * 512 + tid;
    const int r = cl >> 2, d = cl & 3;
    bSrcOff[i] = (size_t)r * 1024 + (size_t)((d ^ ((r >> 1) & 3)) << 4);
  }
  const char* aBase = (const char*)Ap + (size_t)m0 * (AF32 ? 2048 : 1024);
  const char* bBase = (const char*)Bt + (size_t)n0 * 1024;

  auto stage = [&](int kt) {                     // kt compile-time when unrolled
    char* sb = lds + (kt % RING) * SLOT;
#pragma unroll
    for (int i = 0; i < NAG; ++i)
      __builtin_amdgcn_global_load_lds(
        (const __attribute__((address_space(1))) void*)
          (aBase + aSrcOff[i] + (size_t)kt * (AF32 ? 128 : 64)),
        (__attribute__((address_space(3))) void*)(sb + i * 8192 + w * 1024),
        16, 0, 0);
#pragma unroll
    for (int i = 0; i < 2; ++i)
      __builtin_amdgcn_global_load_lds(
        (const __attribute__((address_space(1))) void*)
          (bBase + bSrcOff[i] + (size_t)kt * 64),
        (__attribute__((address_space(3))) void*)(sb + ASLOT + i * 8192 + w * 1024),
        16, 0, 0);
  };

  // ---- frag ds_read offsets (conflict-free per consecutive-8 lanes) ----
  int offA[8], offB[4];
#pragma unroll
  for (int mi = 0; mi < 8; ++mi) {
    const int r = wm * 128 + mi * 16 + lr;
    if constexpr (AF32)
      offA[mi] = r * 128 + (((2 * lq) ^ (r & 7)) << 4);    // hi read = ^16
    else
      offA[mi] = r * 64 + ((lq ^ ((r >> 1) & 3)) << 4);
  }
#pragma unroll
  for (int ni = 0; ni < 4; ++ni) {
    const int rb = wn * 64 + ni * 16 + lr;
    offB[ni] = ASLOT + rb * 64 + ((lq ^ ((rb >> 1) & 3)) << 4);
  }

  f32x4 acc[8][4];
  const f32x4 vz = {0.f, 0.f, 0.f, 0.f};
#pragma unroll
  for (int i = 0; i < 8; ++i)
#pragma unroll
    for (int j = 0; j < 4; ++j) acc[i][j] = vz;

  // ---- prologue: fill ring except one slot; confirm tile 0 ----
#pragma unroll
  for (int p = 0; p < RING - 1; ++p) stage(p);
  if constexpr (AF32) asm volatile("s_waitcnt vmcnt(6)" ::: "memory");
  else                asm volatile("s_waitcnt vmcnt(8)" ::: "memory");
  __builtin_amdgcn_s_barrier();
  __builtin_amdgcn_sched_barrier(0);

#pragma unroll
  for (int t = 0; t < NT; ++t) {
    // stage into slot (t-1)%RING -- consumption confirmed by barrier(t-1)
    if (t + RING - 1 < NT) stage(t + RING - 1);

    const char* sb = lds + (t % RING) * SLOT;

    // B frags for the whole tile
    bf16x8 bfr[4];
#pragma unroll
    for (int ni = 0; ni < 4; ++ni) bfr[ni] = *(const bf16x8*)(sb + offB[ni]);

    if constexpr (AF32) {
      // 2-deep register pipeline over mi-pairs: read(g+1) before MFMA(g)
      f32x4 lo[2][2], hi[2][2];
      bf16x8 afr[2];
#pragma unroll
      for (int p = 0; p < 2; ++p) {
        lo[0][p] = *(const f32x4*)(sb + offA[p]);
        hi[0][p] = *(const f32x4*)(sb + (offA[p] ^ 16));
      }
#pragma unroll
      for (int g = 0; g < 4; ++g) {
        if (g < 3) {
#pragma unroll
          for (int p = 0; p < 2; ++p) {
            lo[(g + 1) & 1][p] = *(const f32x4*)(sb + offA[2 * (g + 1) + p]);
            hi[(g + 1) & 1][p] = *(const f32x4*)(sb + (offA[2 * (g + 1) + p] ^ 16));
          }
        }
#pragma unroll
        for (int p = 0; p < 2; ++p) {
          const f32x4 l = lo[g & 1][p], h2 = hi[g & 1][p];
          unsigned int w0, w1, w2, w3;   // RNE f32->bf16 pack
          asm("v_cvt_pk_bf16_f32 %0, %1, %2" : "=v"(w0) : "v"(l.x), "v"(l.y));
          asm("v_cvt_pk_bf16_f32 %0, %1, %2" : "=v"(w1) : "v"(l.z), "v"(l.w));
          asm("v_cvt_pk_bf16_f32 %0, %1, %2" : "=v"(w2) : "v"(h2.x), "v"(h2.y));
          asm("v_cvt_pk_bf16_f32 %0, %1, %2" : "=v"(w3) : "v"(h2.z), "v"(h2.w));
          u32x4 pw = {w0, w1, w2, w3};
          afr[p] = __builtin_bit_cast(bf16x8, pw);
        }
        __builtin_amdgcn_s_setprio(1);
#pragma unroll
        for (int p = 0; p < 2; ++p)
#pragma unroll
          for (int ni = 0; ni < 4; ++ni)
            acc[2 * g + p][ni] =
                __builtin_amdgcn_mfma_f32_16x16x32_bf16(afr[p], bfr[ni], acc[2 * g + p][ni], 0, 0, 0);
        __builtin_amdgcn_s_setprio(0);
      }
    } else {
      // bf16: read mi-pair g+1 before MFMA group g
      bf16x8 afr[8];
#pragma unroll
      for (int p = 0; p < 2; ++p) afr[p] = *(const bf16x8*)(sb + offA[p]);
#pragma unroll
      for (int g = 0; g < 4; ++g) {
        if (g < 3) {
#pragma unroll
          for (int p = 0; p < 2; ++p)
            afr[2 * (g + 1) + p] = *(const bf16x8*)(sb + offA[2 * (g + 1) + p]);
        }
        __builtin_amdgcn_s_setprio(1);
#pragma unroll
        for (int p = 0; p < 2; ++p)
#pragma unroll
          for (int ni = 0; ni < 4; ++ni)
            acc[2 * g + p][ni] =
                __builtin_amdgcn_mfma_f32_16x16x32_bf16(afr[2 * g + p], bfr[ni], acc[2 * g + p][ni], 0, 0, 0);
        __builtin_amdgcn_s_setprio(0);
      }
    }

    // ---- per-tile gate: tile t+1 landed; deeper prefetches stay in flight ----
    if (t < NT - 1) {
      const int rem  = NT - 2 - t;                      // tiles staged beyond t+1
      const int keep = (rem < RING - 2 ? rem : RING - 2) * GPT;
      if (keep == 8)      asm volatile("s_waitcnt vmcnt(8)" ::: "memory");
      else if (keep == 6) asm volatile("s_waitcnt vmcnt(6)" ::: "memory");
      else if (keep == 4) asm volatile("s_waitcnt vmcnt(4)" ::: "memory");
      else                asm volatile("s_waitcnt vmcnt(0)" ::: "memory");
    }
    __builtin_amdgcn_s_barrier();
    __builtin_amdgcn_sched_barrier(0);
  }

  // ---- epilogue: C/D col=lr, row=lq*4+i ----
#pragma unroll
  for (int ni = 0; ni < 4; ++ni) {
    const int gc = n0 + wn * 64 + ni * 16 + lr;
#pragma unroll
    for (int mi = 0; mi < 8; ++mi) {
      const int gr = m0 + wm * 128 + mi * 16 + lq * 4;
      const f32x4 v = acc[mi][ni];
#pragma unroll
      for (int i = 0; i < 4; ++i) {
        const float val = v[i] + bv[ni];
        if constexpr (AF32)
          ((unsigned short*)Cp)[(size_t)(gr + i) * 512 + gc] = f2bf(val > 0.f ? val : 0.f);
        else
          ((float*)Cp)[(size_t)(gr + i) * 512 + gc] = val;
      }
    }
  }
}

// ---------------------------------------------------------------------------
extern "C" void kernel_launch(void* const* d_in, const int* in_sizes, int n_in,
                              void* d_out, int out_size, void* d_ws, size_t ws_size,
                              hipStream_t stream) {
  (void)in_sizes; (void)n_in; (void)out_size; (void)ws_size;
  const float* x  = (const float*)d_in[0];  // (65536, 512)
  const float* G  = (const float*)d_in[1];  // (512, 4)
  const float* H  = (const float*)d_in[2];  // (512, 4)
  const float* b1 = (const float*)d_in[3];  // (512,)
  const float* W2 = (const float*)d_in[4];  // (512, 512)
  const float* b2 = (const float*)d_in[5];  // (512,)
  float* out = (float*)d_out;               // (65536, 512) f32

  char* ws = (char*)d_ws;                                    // ~72.4 MB
  unsigned short* h   = (unsigned short*)ws;                 // 67,108,864 B
  unsigned short* Wt  = (unsigned short*)(ws + 67108864);    //    524,288 B
  unsigned short* W2t = (unsigned short*)(ws + 67633152);    //    524,288 B
  float*          Wp  = (float*)(ws + 68157440);             //  4,194,304 B

  build_w_partials<<<256, 256, 0, stream>>>(G, H, Wp);
  reduce_transpose_w<<<1024, 256, 0, stream>>>(Wp, Wt);
  transpose_convert_w2<<<1024, 256, 0, stream>>>(W2, W2t);
  gemm_ring<true><<<512, 512, 0, stream>>>((const void*)x, Wt, b1, (void*)h);
  gemm_ring<false><<<512, 512, 0, stream>>>((const void*)h, W2t, b2, (void*)out);
}